// Round 1
// baseline (3802.941 us; speedup 1.0000x reference)
//
#include <hip/hip_runtime.h>

// ---------------------------------------------------------------------------
// ATKT forward, all-f16 MFMA pipeline.
//   prep  -> casts + bias/qvec precompute + exchange-flag zeroing
//   embed -> sa_emb (f32 out) + fused gather row index ridx
//   tgemm -> T tables: T1=se@Wl^T+q0, T0=se@Wr^T+q1, permuted f16 store
//   lstm  -> R4: 8 WGs (4 batch-groups x 2 hidden-halves). Each WG owns 128
//            hidden cols -> all 32 Whh frags fit in VGPRs (no LDS-B reads,
//            was 147KB/step). Partner halves of h exchanged per step through
//            agent-scope (sc1) atomics + counting flags; 1 barrier/step.
//   mlp gemm -> att -> scan (softmax-as-prefix-scan) -> fc gemm (sigmoid)
// ---------------------------------------------------------------------------

typedef _Float16 half8 __attribute__((ext_vector_type(8)));
typedef _Float16 half4 __attribute__((ext_vector_type(4)));
typedef float f32x4 __attribute__((ext_vector_type(4)));

#define BS 32768
#define NC 1000

__device__ __forceinline__ float sigm(float x) {
    return __builtin_amdgcn_rcpf(1.f + __expf(-x));
}
__device__ __forceinline__ float tanh_(float x) {
    float e = __expf(2.f * x);
    return 1.f - 2.f * __builtin_amdgcn_rcpf(e + 1.f);
}

// ---------------------------------------------------------------------------
// prep: f32->f16 casts, bsum=bih+bhh, qvec[0]=ae[1]@Wr^T+bsum, qvec[1]=ae[0]@Wl^T+bsum
// R4: also zeroes the 8 lstm exchange flags (must happen before lstm each launch).
// ---------------------------------------------------------------------------
__global__ void prep_kernel(const float* __restrict__ Wih, const float* __restrict__ fcW,
                            const float* __restrict__ mlpW, const float* __restrict__ se,
                            const float* __restrict__ ae, const float* __restrict__ bih,
                            const float* __restrict__ bhh,
                            _Float16* __restrict__ wih16, _Float16* __restrict__ fcw16,
                            _Float16* __restrict__ mlpw16, _Float16* __restrict__ se16,
                            float* __restrict__ bsum, float* __restrict__ qvec,
                            unsigned* __restrict__ flags) {
    int i = blockIdx.x * 256 + threadIdx.x;
    if (i < 524288) {
        wih16[i] = (_Float16)Wih[i];
    } else if (i < 1048576) {
        int j = i - 524288;                 // fcw padded 1024x512
        int r = j >> 9;
        fcw16[j] = (r < NC) ? (_Float16)fcW[j] : (_Float16)0.f;
    } else if (i < 1081344) {
        int j = i - 1048576;                // mlpw padded 128x256
        int r = j >> 8;
        mlpw16[j] = (r < 80) ? (_Float16)mlpW[j] : (_Float16)0.f;
    } else if (i < 1337600) {
        int j = i - 1081344;                // se 1001x256
        se16[j] = (_Float16)se[j];
    } else if (i < 1338624) {
        int j = i - 1337600;
        bsum[j] = bih[j] + bhh[j];
    } else if (i < 1340672) {
        int j = i - 1338624;                // qvec 2x1024
        int which = j >> 10, col = j & 1023;
        int aerow = (which == 0) ? 1 : 0;   // T1 uses ae[1]@Wr; T0 uses ae[0]@Wl
        int koff  = (which == 0) ? 256 : 0;
        float s = 0.f;
        for (int k = 0; k < 256; k++)
            s += ae[aerow * 256 + k] * Wih[(size_t)col * 512 + koff + k];
        qvec[j] = s + bih[col] + bhh[col];
    } else if (i < 1340680) {
        flags[i - 1340672] = 0;             // R4: lstm exchange flags
    }
}

// ---------------------------------------------------------------------------
// embed: sa_emb f32 output + ridx (row into T table: ans==1 ? sk : 1024+sk)
// ---------------------------------------------------------------------------
__global__ void embed_kernel(const int* __restrict__ skill, const int* __restrict__ answer,
                             const float* __restrict__ se, const float* __restrict__ ae,
                             float* __restrict__ sa_out, int* __restrict__ ridx) {
    int token = blockIdx.x;
    int sk = skill[token], an = answer[token];
    const float* first  = (an == 1) ? (se + (size_t)sk * 256) : (ae + (size_t)an * 256);
    const float* second = (an == 1) ? (ae + (size_t)an * 256) : (se + (size_t)sk * 256);
    int j = threadIdx.x * 4;
    const float* src = (j < 256) ? (first + j) : (second + (j - 256));
    float4 v = *(const float4*)src;
    *(float4*)(sa_out + (size_t)token * 512 + j) = v;
    if (threadIdx.x == 0) ridx[token] = (an == 1) ? sk : (1024 + sk);
}

// ---------------------------------------------------------------------------
// tgemm: T tables (2048x1024), A=se16 (row-clamped), B=wih16 (ldB=512,+koff),
// epilogue adds qvec and stores f16 permuted.
// R4 perm: layout [hc(256)][gate v(4)] so lstm loads half4 = (i,f,g,o)(hc):
//   col = v*256 + hc  ->  perm = hc*4 + v = (col&255)*4 + (col>>8)
// ---------------------------------------------------------------------------
__global__ __launch_bounds__(256) void tgemm_kernel(
        const _Float16* __restrict__ A, const _Float16* __restrict__ Bw,
        const float* __restrict__ qvec, _Float16* __restrict__ Tsw) {
    int bm = blockIdx.x * 128, bn = blockIdx.y * 128;
    int which = bm >> 10;
    int mbase = bm & 1023;
    int koff = which ? 256 : 0;
    int tid = threadIdx.x, wv = tid >> 6, lane = tid & 63;
    int quad = lane >> 4, l16 = lane & 15;
    int wm = (wv & 1) * 64, wn = (wv >> 1) * 64;

    int arow[4];
#pragma unroll
    for (int i = 0; i < 4; i++) {
        int r = mbase + wm + i * 16 + l16;
        arow[i] = (r > 1000) ? 1000 : r;
    }
    const _Float16* Bbase = Bw + (size_t)(bn + wn + l16) * 512 + koff + quad * 8;

    f32x4 acc[4][4] = {};
    for (int kk = 0; kk < 256; kk += 32) {
        half8 a[4], b[4];
#pragma unroll
        for (int i = 0; i < 4; i++)
            a[i] = *(const half8*)(A + (size_t)arow[i] * 256 + quad * 8 + kk);
#pragma unroll
        for (int j = 0; j < 4; j++)
            b[j] = *(const half8*)(Bbase + (size_t)j * 16 * 512 + kk);
#pragma unroll
        for (int i = 0; i < 4; i++)
#pragma unroll
            for (int j = 0; j < 4; j++)
                acc[i][j] = __builtin_amdgcn_mfma_f32_16x16x32_f16(a[i], b[j], acc[i][j], 0, 0, 0);
    }
#pragma unroll
    for (int j = 0; j < 4; j++) {
        int col = bn + wn + j * 16 + l16;
        float qv = qvec[which * 1024 + col];
        int perm = ((col & 255) << 2) | (col >> 8);          // R4
#pragma unroll
        for (int i = 0; i < 4; i++) {
            int row = mbase + wm + i * 16 + quad * 4;
#pragma unroll
            for (int r = 0; r < 4; r++) {
                if (row + r > 1000) continue;
                Tsw[(size_t)((which << 10) + row + r) * 1024 + perm] = (_Float16)(acc[i][j][r] + qv);
            }
        }
    }
}

// ---------------------------------------------------------------------------
// LSTM, R4: 8 WGs x 512 threads. WG bid: batch group g=bid&3, half=bid>>2.
// WG owns hidden cols [half*128, half*128+128): gate cols v*256 + hc, v=0..3.
// All 32 Whh frags (4v x 8k) in VGPRs (128 VGPR) -> zero LDS-B traffic.
// hA double-buffered (1 barrier/step). Per-step cross-WG h-half exchange:
//   - each thread packs its 4 h values (rows quad*4+r) into one u64, stores to
//     X[g][half][t&1] with agent-scope (sc1, write-through) atomic store
//   - per wave: s_waitcnt vmcnt(0); lane0: flag += 1 (publish) THEN spin on
//     partner flag >= 8*(t+1)   (publish-before-spin => no deadlock)
//   - each thread atomically loads partner chunk tid, scatters into hA[nxt]
// Parity double-buffer on X: writer can only reach step t+2 (same parity)
// after partner published t+1, which is after partner consumed X(t). Safe.
// ---------------------------------------------------------------------------
__global__ __launch_bounds__(512, 2) void lstm_kernel(
        const float* __restrict__ Whh,          // [1024][256] f32
        const _Float16* __restrict__ Tsw,       // [2048][1024] f16 permuted
        const int* __restrict__ ridxArr,        // [B*S]
        _Float16* __restrict__ outH,            // [b*512+t][256] f16
        unsigned long long* __restrict__ Xbuf,  // [4][2][2 parity][512] u64
        unsigned* __restrict__ flags) {         // [4][2] counting flags
    int bid = blockIdx.x;
    int g = bid & 3;
    int half = bid >> 2;
    int tid = threadIdx.x, wv = tid >> 6, lane = tid & 63;
    int quad = lane >> 4, l16 = lane & 15;
    int hc = half * 128 + wv * 16 + l16;        // hidden col this thread owns

    __shared__ _Float16 hA[2][4096];            // A-frag order, double-buffered

    // ---- Whh fragments (f32 -> f16), all in VGPRs ----
    half8 rB[32];
#pragma unroll
    for (int v = 0; v < 4; v++) {
#pragma unroll
        for (int k = 0; k < 8; k++) {
            const float* p = Whh + (size_t)(v * 256 + hc) * 256 + k * 32 + quad * 8;
            float4 x0 = *(const float4*)p;
            float4 x1 = *(const float4*)(p + 4);
            half8 hb;
            hb[0] = (_Float16)x0.x; hb[1] = (_Float16)x0.y;
            hb[2] = (_Float16)x0.z; hb[3] = (_Float16)x0.w;
            hb[4] = (_Float16)x1.x; hb[5] = (_Float16)x1.y;
            hb[6] = (_Float16)x1.z; hb[7] = (_Float16)x1.w;
            rB[k * 4 + v] = hb;
        }
    }
    ((float4*)hA[0])[tid] = float4{0.f, 0.f, 0.f, 0.f};   // h_{-1} = 0 (8KB)

    float c[4] = {};
    int tb[4];
    _Float16* po[4];
#pragma unroll
    for (int r = 0; r < 4; r++) {
        int b = g * 16 + quad * 4 + r;
        tb[r] = b * 512;
        po[r] = outH + (size_t)b * 512 * 256 + hc;
    }
    // prologue gathers
    half4 Tcur[4];
    unsigned ridxA[4];
#pragma unroll
    for (int r = 0; r < 4; r++) {
        int r0 = ridxArr[tb[r]];
        Tcur[r] = *(const half4*)(Tsw + (size_t)r0 * 1024 + hc * 4);
        ridxA[r] = ridxArr[tb[r] + 1];
    }

    unsigned* flagW = flags + (g * 2 + half);
    unsigned* flagP = flags + (g * 2 + 1 - half);
    unsigned long long* Xw = Xbuf + (size_t)(g * 2 + half) * 1024;
    unsigned long long* Xp = Xbuf + (size_t)(g * 2 + 1 - half) * 1024;

    // hA scatter bases (f16 index): elem(col,row) -> (col>>5)*512 +
    //   ((col>>3)&3)*128 + row*8 + (col&7); row = quad*4+r folded as quad*32+r*8
    int wbase = (half * 4 + (wv >> 1)) * 512 +
                ((2 * wv + (l16 >> 3)) & 3) * 128 + quad * 32 + (l16 & 7);
    int pbase = ((1 - half) * 4 + (wv >> 1)) * 512 +
                ((2 * wv + (l16 >> 3)) & 3) * 128 + quad * 32 + (l16 & 7);

    __syncthreads();

    int cur = 0;
    for (int t = 0; t < 512; t++) {
        // prefetch next T rows + indices two ahead
        half4 Tnx[4];
        unsigned ridxB[4];
        int tn2 = (t + 2 < 512) ? t + 2 : 511;
#pragma unroll
        for (int r = 0; r < 4; r++)
            Tnx[r] = *(const half4*)(Tsw + (size_t)ridxA[r] * 1024 + hc * 4);
#pragma unroll
        for (int r = 0; r < 4; r++) ridxB[r] = ridxArr[tb[r] + tn2];

        f32x4 acc[4] = {};
#pragma unroll
        for (int k = 0; k < 8; k++) {
            half8 av = *(const half8*)(&hA[cur][k * 512 + lane * 8]);
#pragma unroll
            for (int v = 0; v < 4; v++)
                acc[v] = __builtin_amdgcn_mfma_f32_16x16x32_f16(av, rB[k * 4 + v], acc[v], 0, 0, 0);
        }

        // elementwise gate update (v: 0=i 1=f 2=g 3=o)
        union { _Float16 h4[4]; unsigned long long u; } pk;
        _Float16* hw = &hA[cur ^ 1][0];
#pragma unroll
        for (int r = 0; r < 4; r++) {
            float ii = sigm(acc[0][r] + (float)Tcur[r][0]);
            float ff = sigm(acc[1][r] + (float)Tcur[r][1]);
            float gg = tanh_(acc[2][r] + (float)Tcur[r][2]);
            float oo = sigm(acc[3][r] + (float)Tcur[r][3]);
            c[r] = ff * c[r] + ii * gg;
            float h = oo * tanh_(c[r]);
            _Float16 hf = (_Float16)h;
            pk.h4[r] = hf;
            hw[wbase + r * 8] = hf;            // own half into hA[nxt] (LDS)
        }

        if (t < 511) {
            // publish own half (write-through to coherence point)
            __hip_atomic_store(Xw + (size_t)(t & 1) * 512 + tid, pk.u,
                               __ATOMIC_RELAXED, __HIP_MEMORY_SCOPE_AGENT);
            asm volatile("s_waitcnt vmcnt(0)" ::: "memory");
            if (lane == 0) {
                __hip_atomic_fetch_add(flagW, 1u, __ATOMIC_RELAXED, __HIP_MEMORY_SCOPE_AGENT);
                unsigned need = 8u * (unsigned)(t + 1);
                while (__hip_atomic_load(flagP, __ATOMIC_RELAXED, __HIP_MEMORY_SCOPE_AGENT) < need) { }
            }
            asm volatile("" ::: "memory");     // keep load below the spin
            unsigned long long chv = __hip_atomic_load(
                Xp + (size_t)(t & 1) * 512 + tid,
                __ATOMIC_RELAXED, __HIP_MEMORY_SCOPE_AGENT);
            union { unsigned long long u; _Float16 h4[4]; } upk;
            upk.u = chv;
#pragma unroll
            for (int r = 0; r < 4; r++)
                hw[pbase + r * 8] = upk.h4[r]; // partner half into hA[nxt]
        }

#pragma unroll
        for (int r = 0; r < 4; r++) {
            po[r][0] = pk.h4[r];               // global outH store (post-exchange)
            po[r] += 256;
            Tcur[r] = Tnx[r];
            ridxA[r] = ridxB[r];
        }
        __syncthreads();                       // hA[nxt] complete for step t+1
        cur ^= 1;
    }
}

// ---------------------------------------------------------------------------
// Generic f16 MFMA GEMM: C = A @ Bw^T (+bias), epi 1 = sigmoid. Direct-global.
// ---------------------------------------------------------------------------
__global__ __launch_bounds__(256) void gemm_f16(
        const _Float16* __restrict__ A, const _Float16* __restrict__ Bw,
        const float* __restrict__ bias, float* __restrict__ C,
        int K, int ldC, int Nstore, int epi) {
    int bm = blockIdx.x * 128, bn = blockIdx.y * 128;
    int tid = threadIdx.x, wv = tid >> 6, lane = tid & 63;
    int quad = lane >> 4, l16 = lane & 15;
    int wm = (wv & 1) * 64, wn = (wv >> 1) * 64;

    const _Float16* Abase = A + (size_t)(bm + wm + l16) * K + quad * 8;
    const _Float16* Bbase = Bw + (size_t)(bn + wn + l16) * K + quad * 8;

    f32x4 acc[4][4] = {};
    for (int kk = 0; kk < K; kk += 32) {
        half8 a[4], b[4];
#pragma unroll
        for (int i = 0; i < 4; i++) a[i] = *(const half8*)(Abase + (size_t)i * 16 * K + kk);
#pragma unroll
        for (int j = 0; j < 4; j++) b[j] = *(const half8*)(Bbase + (size_t)j * 16 * K + kk);
#pragma unroll
        for (int i = 0; i < 4; i++)
#pragma unroll
            for (int j = 0; j < 4; j++)
                acc[i][j] = __builtin_amdgcn_mfma_f32_16x16x32_f16(a[i], b[j], acc[i][j], 0, 0, 0);
    }
#pragma unroll
    for (int j = 0; j < 4; j++) {
        int col = bn + wn + j * 16 + l16;
        if (col >= Nstore) continue;
        float bv = bias ? bias[col] : 0.f;
#pragma unroll
        for (int i = 0; i < 4; i++) {
            int row0 = bm + wm + i * 16 + quad * 4;
#pragma unroll
            for (int r = 0; r < 4; r++) {
                float v = acc[i][j][r] + bv;
                if (epi == 1) v = sigm(v);
                C[(size_t)(row0 + r) * ldC + col] = v;
            }
        }
    }
}

// ---------------------------------------------------------------------------
__global__ void att_kernel(const float* __restrict__ mlpout, const float* __restrict__ simW,
                           float* __restrict__ att) {
    int m = blockIdx.x * 256 + threadIdx.x;
    float s = 0.f;
#pragma unroll
    for (int d = 0; d < 80; d += 4) {
        float4 v = *(const float4*)(mlpout + (size_t)m * 80 + d);
        float4 w = *(const float4*)(simW + d);
        s += tanh_(v.x) * w.x + tanh_(v.y) * w.y + tanh_(v.z) * w.z + tanh_(v.w) * w.w;
    }
    att[m] = s;
}

// ---------------------------------------------------------------------------
// Attention as prefix scan; writes final = [attn_cum_1 | out] f16.
// ---------------------------------------------------------------------------
__global__ __launch_bounds__(256) void scan_kernel(const float* __restrict__ att,
                                                   const _Float16* __restrict__ outH,
                                                   _Float16* __restrict__ finalB) {
    int b = blockIdx.x, d = threadIdx.x;
    __shared__ float w_s[512];
    for (int i = d; i < 512; i += 256) w_s[i] = __expf(att[(size_t)b * 512 + i]);
    __syncthreads();

    float S = 0.f, W = 0.f, C = 0.f;
    const _Float16* op = outH + (size_t)b * 512 * 256 + d;
    _Float16* fp = finalB + (size_t)b * 512 * 512 + d;
    for (int i = 0; i < 512; i++) {
        float w = w_s[i];
        float ov = (float)op[(size_t)i * 256];
        S += w * ov;
        W += w;
        float ao = S * __builtin_amdgcn_rcpf(W);
        fp[(size_t)i * 512]       = (_Float16)C;
        fp[(size_t)i * 512 + 256] = (_Float16)ov;
        C += ao;
    }
}

// ---------------------------------------------------------------------------
extern "C" void kernel_launch(void* const* d_in, const int* in_sizes, int n_in,
                              void* d_out, int out_size, void* d_ws, size_t ws_size,
                              hipStream_t stream) {
    const int*   skill      = (const int*)d_in[0];
    const int*   answer     = (const int*)d_in[1];
    const float* skill_emb  = (const float*)d_in[2];
    const float* answer_emb = (const float*)d_in[3];
    const float* Wih        = (const float*)d_in[4];
    const float* Whh        = (const float*)d_in[5];
    const float* bih        = (const float*)d_in[6];
    const float* bhh        = (const float*)d_in[7];
    const float* mlp_W      = (const float*)d_in[8];
    const float* mlp_b      = (const float*)d_in[9];
    const float* sim_W      = (const float*)d_in[10];
    const float* fc_W       = (const float*)d_in[11];
    const float* fc_b       = (const float*)d_in[12];

    float* res    = (float*)d_out;               // [32768][1000]
    float* sa_out = res + (size_t)BS * NC;       // [32768][512]

    char* ws = (char*)d_ws;
    _Float16* outH   = (_Float16*)(ws);                 // 16,777,216 B
    _Float16* finalB = (_Float16*)(ws + 16777216);      // 33,554,432
    _Float16* wih16  = (_Float16*)(ws + 50331648);      //  1,048,576
    _Float16* fcw16  = (_Float16*)(ws + 51380224);      //  1,048,576
    _Float16* mlpw16 = (_Float16*)(ws + 52428800);      //     65,536
    _Float16* se16   = (_Float16*)(ws + 52494336);      //    524,288 (512,512 used)
    float*    bsum   = (float*)(ws + 53018624);         //      4,096
    float*    qvec   = (float*)(ws + 53022720);         //      8,192
    float*    att    = (float*)(ws + 53030912);         //    131,072
    float*    mlpout = (float*)(ws + 53161984);         // 10,485,760
    _Float16* Tsw    = (_Float16*)(ws + 63647744);      //  4,194,304
    int*      ridx   = (int*)(ws + 67842048);           //    131,072

    // R4: X exchange buffers + flags live in the mlpout region (mlpout is only
    // written by the mlp gemm, which runs strictly after lstm completes).
    unsigned long long* Xbuf = (unsigned long long*)(ws + 53161984);   // 65,536 B
    unsigned*           flg  = (unsigned*)(ws + 53161984 + 65536);     //      32 B

    (void)bsum; (void)in_sizes; (void)n_in; (void)out_size; (void)ws_size;

    hipLaunchKernelGGL(prep_kernel, dim3(5238), dim3(256), 0, stream,
                       Wih, fc_W, mlp_W, skill_emb, answer_emb, bih, bhh,
                       wih16, fcw16, mlpw16, se16, bsum, qvec, flg);
    hipLaunchKernelGGL(embed_kernel, dim3(BS), dim3(128), 0, stream,
                       skill, answer, skill_emb, answer_emb, sa_out, ridx);
    hipLaunchKernelGGL(tgemm_kernel, dim3(16, 8), dim3(256), 0, stream,
                       se16, wih16, qvec, Tsw);

    hipLaunchKernelGGL(lstm_kernel, dim3(8), dim3(512), 0, stream,
                       Whh, Tsw, ridx, outH, Xbuf, flg);

    hipLaunchKernelGGL(gemm_f16, dim3(256, 1), dim3(256), 0, stream,
                       outH, mlpw16, mlp_b, mlpout, 256, 80, 80, 0);
    hipLaunchKernelGGL(att_kernel, dim3(128), dim3(256), 0, stream, mlpout, sim_W, att);
    hipLaunchKernelGGL(scan_kernel, dim3(64), dim3(256), 0, stream, att, outH, finalB);
    hipLaunchKernelGGL(gemm_f16, dim3(256, 8), dim3(256), 0, stream,
                       finalB, fcw16, fc_b, res, 512, 1000, 1000, 1);
}

// Round 2
// 2078.372 us; speedup vs baseline: 1.8298x; 1.8298x over previous
//
#include <hip/hip_runtime.h>

// ---------------------------------------------------------------------------
// ATKT forward, all-f16 MFMA pipeline.
//   prep  -> casts + bias/qvec precompute
//   embed -> sa_emb (f32 out) + fused gather row index ridx
//   tgemm -> T tables: T1=se@Wl^T+q0, T0=se@Wr^T+q1, permuted f16 store
//   lstm  -> R5: 4 WGs x 8 waves (R3 structure). Whh f16: 46 frag/thread VGPR
//            + 18 frag/wave LDS. hA double-buffered -> ONE barrier/step
//            (R3 had 2); outH global stores issued AFTER the barrier so the
//            vmcnt(0) drain overlaps the next step's MFMA+trans phase.
//            LDS = 147456 (ldsB) + 16384 (hA x2) = 163840 = the 160 KiB cap.
//   mlp gemm -> att -> scan (softmax-as-prefix-scan) -> fc gemm (sigmoid)
// R4 post-mortem: N-split across 2 WGs with per-step agent-scope exchange cost
// ~3.5us/step of coherence round-trips (6.76 vs 3.16 us/step) -> reverted.
// ---------------------------------------------------------------------------

typedef _Float16 half8 __attribute__((ext_vector_type(8)));
typedef float f32x4 __attribute__((ext_vector_type(4)));

#define BS 32768
#define NC 1000

__device__ __forceinline__ float sigm(float x) {
    return __builtin_amdgcn_rcpf(1.f + __expf(-x));
}
__device__ __forceinline__ float tanh_(float x) {
    float e = __expf(2.f * x);
    return 1.f - 2.f * __builtin_amdgcn_rcpf(e + 1.f);
}

// ---------------------------------------------------------------------------
// prep: f32->f16 casts, bsum=bih+bhh, qvec[0]=ae[1]@Wr^T+bsum, qvec[1]=ae[0]@Wl^T+bsum
// ---------------------------------------------------------------------------
__global__ void prep_kernel(const float* __restrict__ Wih, const float* __restrict__ fcW,
                            const float* __restrict__ mlpW, const float* __restrict__ se,
                            const float* __restrict__ ae, const float* __restrict__ bih,
                            const float* __restrict__ bhh,
                            _Float16* __restrict__ wih16, _Float16* __restrict__ fcw16,
                            _Float16* __restrict__ mlpw16, _Float16* __restrict__ se16,
                            float* __restrict__ bsum, float* __restrict__ qvec) {
    int i = blockIdx.x * 256 + threadIdx.x;
    if (i < 524288) {
        wih16[i] = (_Float16)Wih[i];
    } else if (i < 1048576) {
        int j = i - 524288;                 // fcw padded 1024x512
        int r = j >> 9;
        fcw16[j] = (r < NC) ? (_Float16)fcW[j] : (_Float16)0.f;
    } else if (i < 1081344) {
        int j = i - 1048576;                // mlpw padded 128x256
        int r = j >> 8;
        mlpw16[j] = (r < 80) ? (_Float16)mlpW[j] : (_Float16)0.f;
    } else if (i < 1337600) {
        int j = i - 1081344;                // se 1001x256
        se16[j] = (_Float16)se[j];
    } else if (i < 1338624) {
        int j = i - 1337600;
        bsum[j] = bih[j] + bhh[j];
    } else if (i < 1340672) {
        int j = i - 1338624;                // qvec 2x1024
        int which = j >> 10, col = j & 1023;
        int aerow = (which == 0) ? 1 : 0;   // T1 uses ae[1]@Wr; T0 uses ae[0]@Wl
        int koff  = (which == 0) ? 256 : 0;
        float s = 0.f;
        for (int k = 0; k < 256; k++)
            s += ae[aerow * 256 + k] * Wih[(size_t)col * 512 + koff + k];
        qvec[j] = s + bih[col] + bhh[col];
    }
}

// ---------------------------------------------------------------------------
// embed: sa_emb f32 output + ridx (row into T table: ans==1 ? sk : 1024+sk)
// ---------------------------------------------------------------------------
__global__ void embed_kernel(const int* __restrict__ skill, const int* __restrict__ answer,
                             const float* __restrict__ se, const float* __restrict__ ae,
                             float* __restrict__ sa_out, int* __restrict__ ridx) {
    int token = blockIdx.x;
    int sk = skill[token], an = answer[token];
    const float* first  = (an == 1) ? (se + (size_t)sk * 256) : (ae + (size_t)an * 256);
    const float* second = (an == 1) ? (ae + (size_t)an * 256) : (se + (size_t)sk * 256);
    int j = threadIdx.x * 4;
    const float* src = (j < 256) ? (first + j) : (second + (j - 256));
    float4 v = *(const float4*)src;
    *(float4*)(sa_out + (size_t)token * 512 + j) = v;
    if (threadIdx.x == 0) ridx[token] = (an == 1) ? sk : (1024 + sk);
}

// ---------------------------------------------------------------------------
// tgemm: T tables (2048x1024), A=se16 (row-clamped), B=wih16 (ldB=512,+koff),
// epilogue adds qvec and stores f16 permuted: T_sw[row*1024 + w*128+l16*8+v],
// where col = (v>>1)*256 + 32w + (v&1)*16 + l16.
// ---------------------------------------------------------------------------
__global__ __launch_bounds__(256) void tgemm_kernel(
        const _Float16* __restrict__ A, const _Float16* __restrict__ Bw,
        const float* __restrict__ qvec, _Float16* __restrict__ Tsw) {
    int bm = blockIdx.x * 128, bn = blockIdx.y * 128;
    int which = bm >> 10;
    int mbase = bm & 1023;
    int koff = which ? 256 : 0;
    int tid = threadIdx.x, wv = tid >> 6, lane = tid & 63;
    int quad = lane >> 4, l16 = lane & 15;
    int wm = (wv & 1) * 64, wn = (wv >> 1) * 64;

    int arow[4];
#pragma unroll
    for (int i = 0; i < 4; i++) {
        int r = mbase + wm + i * 16 + l16;
        arow[i] = (r > 1000) ? 1000 : r;
    }
    const _Float16* Bbase = Bw + (size_t)(bn + wn + l16) * 512 + koff + quad * 8;

    f32x4 acc[4][4] = {};
    for (int kk = 0; kk < 256; kk += 32) {
        half8 a[4], b[4];
#pragma unroll
        for (int i = 0; i < 4; i++)
            a[i] = *(const half8*)(A + (size_t)arow[i] * 256 + quad * 8 + kk);
#pragma unroll
        for (int j = 0; j < 4; j++)
            b[j] = *(const half8*)(Bbase + (size_t)j * 16 * 512 + kk);
#pragma unroll
        for (int i = 0; i < 4; i++)
#pragma unroll
            for (int j = 0; j < 4; j++)
                acc[i][j] = __builtin_amdgcn_mfma_f32_16x16x32_f16(a[i], b[j], acc[i][j], 0, 0, 0);
    }
#pragma unroll
    for (int j = 0; j < 4; j++) {
        int col = bn + wn + j * 16 + l16;
        float qv = qvec[which * 1024 + col];
        int perm = ((col & 255) >> 5) * 128 + (col & 15) * 8 + ((col >> 8) * 2 + ((col >> 4) & 1));
#pragma unroll
        for (int i = 0; i < 4; i++) {
            int row = mbase + wm + i * 16 + quad * 4;
#pragma unroll
            for (int r = 0; r < 4; r++) {
                if (row + r > 1000) continue;
                Tsw[(size_t)((which << 10) + row + r) * 1024 + perm] = (_Float16)(acc[i][j][r] + qv);
            }
        }
    }
}

// ---------------------------------------------------------------------------
// LSTM, R5. 4 WGs x 512 threads (8 waves, 2/SIMD, <=256 unified VGPR).
// Wave w owns hidden cols [32w,32w+32): gate cols (v>>1)*256 + 32w + (v&1)*16 + l16.
// Whh f16 frags: (v,k) k<5 or (k==5,v<6) in VGPRs (46), rest in LDS (18/wave).
// hA double-buffered in A-frag order: step t reads hA[cur], writes hA[cur^1]
// directly from the gate loop -> ONE __syncthreads per step. outH global
// stores happen post-barrier so their vmcnt drain overlaps next step.
// ---------------------------------------------------------------------------
__global__ __launch_bounds__(512, 2) void lstm_kernel(
        const float* __restrict__ Whh,          // [1024][256] f32
        const _Float16* __restrict__ Tsw,       // [2048][1024] f16 permuted
        const int* __restrict__ ridxArr,        // [B*S]
        _Float16* __restrict__ outH) {          // [b*512+t][256] f16
    int g16 = blockIdx.x;
    int tid = threadIdx.x, wv = tid >> 6, lane = tid & 63;
    int quad = lane >> 4, l16 = lane & 15;

    extern __shared__ char smem[];
    _Float16* ldsB = (_Float16*)smem;                  // 8 waves * 18 frags * 512 f16 = 147456 B
    _Float16* hA   = (_Float16*)(smem + 147456);       // 2 x 8 KB, A-frag order, double-buffered

    // ---- fill Whh fragments (f32 -> f16) ----
    half8 rB[46];
#pragma unroll
    for (int v = 0; v < 8; v++) {
#pragma unroll
        for (int k = 0; k < 8; k++) {
            int col = (v >> 1) * 256 + wv * 32 + (v & 1) * 16 + l16;
            const float* p = Whh + (size_t)col * 256 + k * 32 + quad * 8;
            float4 x0 = *(const float4*)p;
            float4 x1 = *(const float4*)(p + 4);
            half8 hb;
            hb[0] = (_Float16)x0.x; hb[1] = (_Float16)x0.y; hb[2] = (_Float16)x0.z; hb[3] = (_Float16)x0.w;
            hb[4] = (_Float16)x1.x; hb[5] = (_Float16)x1.y; hb[6] = (_Float16)x1.z; hb[7] = (_Float16)x1.w;
            if (k < 5) rB[k * 8 + v] = hb;
            else if (k == 5 && v < 6) rB[40 + v] = hb;
            else {
                int f = (k == 5) ? (v - 6) : ((k == 6) ? (2 + v) : (10 + v));
                *(half8*)(ldsB + ((size_t)wv * 18 + f) * 512 + lane * 8) = hb;
            }
        }
    }
    // zero h buffer 0 (8 KB)
    ((float4*)hA)[tid] = float4{0.f, 0.f, 0.f, 0.f};

    float c[2][4] = {};
    int tb[4];
    _Float16* po[4];
#pragma unroll
    for (int r = 0; r < 4; r++) {
        int b = g16 * 16 + quad * 4 + r;
        tb[r] = b * 512;
        po[r] = outH + (size_t)b * 512 * 256 + wv * 32 + l16;
    }
    // prologue gathers
    half8 Tcur[4];
    unsigned ridxA[4];
#pragma unroll
    for (int r = 0; r < 4; r++) {
        int r0 = ridxArr[tb[r]];
        Tcur[r] = *(const half8*)(Tsw + (size_t)r0 * 1024 + wv * 128 + l16 * 8);
        ridxA[r] = ridxArr[tb[r] + 1];
    }
    __syncthreads();

    int cur = 0;
    for (int t = 0; t < 512; t++) {
        // prefetch next T rows + indices two ahead (drained by this step's barrier)
        half8 Tnx[4];
        unsigned ridxB[4];
        int tn2 = (t + 2 < 512) ? t + 2 : 511;
#pragma unroll
        for (int r = 0; r < 4; r++)
            Tnx[r] = *(const half8*)(Tsw + (size_t)ridxA[r] * 1024 + wv * 128 + l16 * 8);
#pragma unroll
        for (int r = 0; r < 4; r++) ridxB[r] = ridxArr[tb[r] + tn2];

        f32x4 acc[8];
#pragma unroll
        for (int v = 0; v < 8; v++) acc[v] = f32x4{0.f, 0.f, 0.f, 0.f};

        const _Float16* hAc = hA + (cur << 12);
#pragma unroll
        for (int k = 0; k < 8; k++) {
            half8 av = *(const half8*)(hAc + k * 512 + lane * 8);
#pragma unroll
            for (int v = 0; v < 8; v++) {
                half8 bv;
                if (k < 5) bv = rB[k * 8 + v];
                else if (k == 5 && v < 6) bv = rB[40 + v];
                else {
                    int f = (k == 5) ? (v - 6) : ((k == 6) ? (2 + v) : (10 + v));
                    bv = *(const half8*)(ldsB + ((size_t)wv * 18 + f) * 512 + lane * 8);
                }
                acc[v] = __builtin_amdgcn_mfma_f32_16x16x32_f16(av, bv, acc[v], 0, 0, 0);
            }
        }

        // gate math; write new h straight into the OTHER hA buffer (no hazard:
        // nobody reads hA[cur^1] this step)
        _Float16 hw[2][4];
        _Float16* hAn = hA + ((cur ^ 1) << 12);
#pragma unroll
        for (int j = 0; j < 2; j++) {
#pragma unroll
            for (int r = 0; r < 4; r++) {
                float ii = sigm(acc[0 + j][r] + (float)Tcur[r][0 + j]);
                float ff = sigm(acc[2 + j][r] + (float)Tcur[r][2 + j]);
                float gg = tanh_(acc[4 + j][r] + (float)Tcur[r][4 + j]);
                float oo = sigm(acc[6 + j][r] + (float)Tcur[r][6 + j]);
                c[j][r] = ff * c[j][r] + ii * gg;
                float h = oo * tanh_(c[j][r]);
                _Float16 hf = (_Float16)h;
                hw[j][r] = hf;
                hAn[wv * 512 + (2 * j + (l16 >> 3)) * 128 + (quad * 4 + r) * 8 + (l16 & 7)] = hf;
            }
        }
        __syncthreads();   // hA[cur^1] complete for step t+1
        cur ^= 1;

        // post-barrier: outH stores drain during next step's compute phase
#pragma unroll
        for (int r = 0; r < 4; r++) {
            po[r][0]  = hw[0][r];
            po[r][16] = hw[1][r];
            po[r] += 256;
            Tcur[r] = Tnx[r];
            ridxA[r] = ridxB[r];
        }
    }
}

// ---------------------------------------------------------------------------
// Generic f16 MFMA GEMM: C = A @ Bw^T (+bias), epi 1 = sigmoid. Direct-global.
// ---------------------------------------------------------------------------
__global__ __launch_bounds__(256) void gemm_f16(
        const _Float16* __restrict__ A, const _Float16* __restrict__ Bw,
        const float* __restrict__ bias, float* __restrict__ C,
        int K, int ldC, int Nstore, int epi) {
    int bm = blockIdx.x * 128, bn = blockIdx.y * 128;
    int tid = threadIdx.x, wv = tid >> 6, lane = tid & 63;
    int quad = lane >> 4, l16 = lane & 15;
    int wm = (wv & 1) * 64, wn = (wv >> 1) * 64;

    const _Float16* Abase = A + (size_t)(bm + wm + l16) * K + quad * 8;
    const _Float16* Bbase = Bw + (size_t)(bn + wn + l16) * K + quad * 8;

    f32x4 acc[4][4] = {};
    for (int kk = 0; kk < K; kk += 32) {
        half8 a[4], b[4];
#pragma unroll
        for (int i = 0; i < 4; i++) a[i] = *(const half8*)(Abase + (size_t)i * 16 * K + kk);
#pragma unroll
        for (int j = 0; j < 4; j++) b[j] = *(const half8*)(Bbase + (size_t)j * 16 * K + kk);
#pragma unroll
        for (int i = 0; i < 4; i++)
#pragma unroll
            for (int j = 0; j < 4; j++)
                acc[i][j] = __builtin_amdgcn_mfma_f32_16x16x32_f16(a[i], b[j], acc[i][j], 0, 0, 0);
    }
#pragma unroll
    for (int j = 0; j < 4; j++) {
        int col = bn + wn + j * 16 + l16;
        if (col >= Nstore) continue;
        float bv = bias ? bias[col] : 0.f;
#pragma unroll
        for (int i = 0; i < 4; i++) {
            int row0 = bm + wm + i * 16 + quad * 4;
#pragma unroll
            for (int r = 0; r < 4; r++) {
                float v = acc[i][j][r] + bv;
                if (epi == 1) v = sigm(v);
                C[(size_t)(row0 + r) * ldC + col] = v;
            }
        }
    }
}

// ---------------------------------------------------------------------------
__global__ void att_kernel(const float* __restrict__ mlpout, const float* __restrict__ simW,
                           float* __restrict__ att) {
    int m = blockIdx.x * 256 + threadIdx.x;
    float s = 0.f;
#pragma unroll
    for (int d = 0; d < 80; d += 4) {
        float4 v = *(const float4*)(mlpout + (size_t)m * 80 + d);
        float4 w = *(const float4*)(simW + d);
        s += tanh_(v.x) * w.x + tanh_(v.y) * w.y + tanh_(v.z) * w.z + tanh_(v.w) * w.w;
    }
    att[m] = s;
}

// ---------------------------------------------------------------------------
// Attention as prefix scan; writes final = [attn_cum_1 | out] f16.
// ---------------------------------------------------------------------------
__global__ __launch_bounds__(256) void scan_kernel(const float* __restrict__ att,
                                                   const _Float16* __restrict__ outH,
                                                   _Float16* __restrict__ finalB) {
    int b = blockIdx.x, d = threadIdx.x;
    __shared__ float w_s[512];
    for (int i = d; i < 512; i += 256) w_s[i] = __expf(att[(size_t)b * 512 + i]);
    __syncthreads();

    float S = 0.f, W = 0.f, C = 0.f;
    const _Float16* op = outH + (size_t)b * 512 * 256 + d;
    _Float16* fp = finalB + (size_t)b * 512 * 512 + d;
    for (int i = 0; i < 512; i++) {
        float w = w_s[i];
        float ov = (float)op[(size_t)i * 256];
        S += w * ov;
        W += w;
        float ao = S * __builtin_amdgcn_rcpf(W);
        fp[(size_t)i * 512]       = (_Float16)C;
        fp[(size_t)i * 512 + 256] = (_Float16)ov;
        C += ao;
    }
}

// ---------------------------------------------------------------------------
extern "C" void kernel_launch(void* const* d_in, const int* in_sizes, int n_in,
                              void* d_out, int out_size, void* d_ws, size_t ws_size,
                              hipStream_t stream) {
    const int*   skill      = (const int*)d_in[0];
    const int*   answer     = (const int*)d_in[1];
    const float* skill_emb  = (const float*)d_in[2];
    const float* answer_emb = (const float*)d_in[3];
    const float* Wih        = (const float*)d_in[4];
    const float* Whh        = (const float*)d_in[5];
    const float* bih        = (const float*)d_in[6];
    const float* bhh        = (const float*)d_in[7];
    const float* mlp_W      = (const float*)d_in[8];
    const float* mlp_b      = (const float*)d_in[9];
    const float* sim_W      = (const float*)d_in[10];
    const float* fc_W       = (const float*)d_in[11];
    const float* fc_b       = (const float*)d_in[12];

    float* res    = (float*)d_out;               // [32768][1000]
    float* sa_out = res + (size_t)BS * NC;       // [32768][512]

    char* ws = (char*)d_ws;
    _Float16* outH   = (_Float16*)(ws);                 // 16,777,216 B
    _Float16* finalB = (_Float16*)(ws + 16777216);      // 33,554,432
    _Float16* wih16  = (_Float16*)(ws + 50331648);      //  1,048,576
    _Float16* fcw16  = (_Float16*)(ws + 51380224);      //  1,048,576
    _Float16* mlpw16 = (_Float16*)(ws + 52428800);      //     65,536
    _Float16* se16   = (_Float16*)(ws + 52494336);      //    524,288 (512,512 used)
    float*    bsum   = (float*)(ws + 53018624);         //      4,096
    float*    qvec   = (float*)(ws + 53022720);         //      8,192
    float*    att    = (float*)(ws + 53030912);         //    131,072
    float*    mlpout = (float*)(ws + 53161984);         // 10,485,760
    _Float16* Tsw    = (_Float16*)(ws + 63647744);      //  4,194,304
    int*      ridx   = (int*)(ws + 67842048);           //    131,072

    (void)bsum; (void)in_sizes; (void)n_in; (void)out_size; (void)ws_size;

    hipLaunchKernelGGL(prep_kernel, dim3(5238), dim3(256), 0, stream,
                       Wih, fc_W, mlp_W, skill_emb, answer_emb, bih, bhh,
                       wih16, fcw16, mlpw16, se16, bsum, qvec);
    hipLaunchKernelGGL(embed_kernel, dim3(BS), dim3(128), 0, stream,
                       skill, answer, skill_emb, answer_emb, sa_out, ridx);
    hipLaunchKernelGGL(tgemm_kernel, dim3(16, 8), dim3(256), 0, stream,
                       se16, wih16, qvec, Tsw);

    hipFuncSetAttribute((const void*)lstm_kernel,
                        hipFuncAttributeMaxDynamicSharedMemorySize, 163840);
    hipLaunchKernelGGL(lstm_kernel, dim3(4), dim3(512), 163840, stream,
                       Whh, Tsw, ridx, outH);

    hipLaunchKernelGGL(gemm_f16, dim3(256, 1), dim3(256), 0, stream,
                       outH, mlpw16, mlp_b, mlpout, 256, 80, 80, 0);
    hipLaunchKernelGGL(att_kernel, dim3(128), dim3(256), 0, stream, mlpout, sim_W, att);
    hipLaunchKernelGGL(scan_kernel, dim3(64), dim3(256), 0, stream, att, outH, finalB);
    hipLaunchKernelGGL(gemm_f16, dim3(256, 8), dim3(256), 0, stream,
                       finalB, fcw16, fc_b, res, 512, 1000, 1000, 1);
}

// Round 3
// 1312.352 us; speedup vs baseline: 2.8978x; 1.5837x over previous
//
#include <hip/hip_runtime.h>

// ---------------------------------------------------------------------------
// ATKT forward, all-f16 MFMA pipeline.
//   prep  -> casts + bias/qvec precompute
//   embed -> sa_emb (f32 out) + fused gather row index ridx
//   tgemm -> T tables: T1=se@Wl^T+q0, T0=se@Wr^T+q1, permuted f16 store
//   lstm  -> R6: 32 WGs x 2 batch rows. Per-wave MFMA count is invariant
//            (128/SIMD/step = the matrix floor), but gate math is spread
//            1 update/lane via an in-wave LDS acc-redistribution (no extra
//            barrier): trans per lane 40 -> 5. Whh frags: 48 VGPR + 16 LDS.
//   mlp gemm -> att -> scan (softmax-as-prefix-scan) -> fc gemm (sigmoid)
// R5 post-mortem: barrier removal was neutral -> step time = MFMA phase
// (~2500 cyc/SIMD, invariant) + gate phase (~3500 cyc, per-LANE trans).
// R6 attacks the gate phase; matrix pipe becomes the floor.
// ---------------------------------------------------------------------------

typedef _Float16 half8 __attribute__((ext_vector_type(8)));
typedef float f32x4 __attribute__((ext_vector_type(4)));

#define BS 32768
#define NC 1000

__device__ __forceinline__ float sigm(float x) {
    return __builtin_amdgcn_rcpf(1.f + __expf(-x));
}
__device__ __forceinline__ float tanh_(float x) {
    float e = __expf(2.f * x);
    return 1.f - 2.f * __builtin_amdgcn_rcpf(e + 1.f);
}

// ---------------------------------------------------------------------------
// prep: f32->f16 casts, bsum=bih+bhh, qvec[0]=ae[1]@Wr^T+bsum, qvec[1]=ae[0]@Wl^T+bsum
// ---------------------------------------------------------------------------
__global__ void prep_kernel(const float* __restrict__ Wih, const float* __restrict__ fcW,
                            const float* __restrict__ mlpW, const float* __restrict__ se,
                            const float* __restrict__ ae, const float* __restrict__ bih,
                            const float* __restrict__ bhh,
                            _Float16* __restrict__ wih16, _Float16* __restrict__ fcw16,
                            _Float16* __restrict__ mlpw16, _Float16* __restrict__ se16,
                            float* __restrict__ bsum, float* __restrict__ qvec) {
    int i = blockIdx.x * 256 + threadIdx.x;
    if (i < 524288) {
        wih16[i] = (_Float16)Wih[i];
    } else if (i < 1048576) {
        int j = i - 524288;                 // fcw padded 1024x512
        int r = j >> 9;
        fcw16[j] = (r < NC) ? (_Float16)fcW[j] : (_Float16)0.f;
    } else if (i < 1081344) {
        int j = i - 1048576;                // mlpw padded 128x256
        int r = j >> 8;
        mlpw16[j] = (r < 80) ? (_Float16)mlpW[j] : (_Float16)0.f;
    } else if (i < 1337600) {
        int j = i - 1081344;                // se 1001x256
        se16[j] = (_Float16)se[j];
    } else if (i < 1338624) {
        int j = i - 1337600;
        bsum[j] = bih[j] + bhh[j];
    } else if (i < 1340672) {
        int j = i - 1338624;                // qvec 2x1024
        int which = j >> 10, col = j & 1023;
        int aerow = (which == 0) ? 1 : 0;   // T1 uses ae[1]@Wr; T0 uses ae[0]@Wl
        int koff  = (which == 0) ? 256 : 0;
        float s = 0.f;
        for (int k = 0; k < 256; k++)
            s += ae[aerow * 256 + k] * Wih[(size_t)col * 512 + koff + k];
        qvec[j] = s + bih[col] + bhh[col];
    }
}

// ---------------------------------------------------------------------------
// embed: sa_emb f32 output + ridx (row into T table: ans==1 ? sk : 1024+sk)
// ---------------------------------------------------------------------------
__global__ void embed_kernel(const int* __restrict__ skill, const int* __restrict__ answer,
                             const float* __restrict__ se, const float* __restrict__ ae,
                             float* __restrict__ sa_out, int* __restrict__ ridx) {
    int token = blockIdx.x;
    int sk = skill[token], an = answer[token];
    const float* first  = (an == 1) ? (se + (size_t)sk * 256) : (ae + (size_t)an * 256);
    const float* second = (an == 1) ? (ae + (size_t)an * 256) : (se + (size_t)sk * 256);
    int j = threadIdx.x * 4;
    const float* src = (j < 256) ? (first + j) : (second + (j - 256));
    float4 v = *(const float4*)src;
    *(float4*)(sa_out + (size_t)token * 512 + j) = v;
    if (threadIdx.x == 0) ridx[token] = (an == 1) ? sk : (1024 + sk);
}

// ---------------------------------------------------------------------------
// tgemm: T tables (2048x1024), A=se16 (row-clamped), B=wih16 (ldB=512,+koff),
// epilogue adds qvec and stores f16 permuted: T_sw[row*1024 + w*128+l16*8+v],
// where col = (v>>1)*256 + 32w + (v&1)*16 + l16.
// (half8 at (w,l16) = 4 gates x 2 hidden cols {l16, l16+16} of wave w.)
// ---------------------------------------------------------------------------
__global__ __launch_bounds__(256) void tgemm_kernel(
        const _Float16* __restrict__ A, const _Float16* __restrict__ Bw,
        const float* __restrict__ qvec, _Float16* __restrict__ Tsw) {
    int bm = blockIdx.x * 128, bn = blockIdx.y * 128;
    int which = bm >> 10;
    int mbase = bm & 1023;
    int koff = which ? 256 : 0;
    int tid = threadIdx.x, wv = tid >> 6, lane = tid & 63;
    int quad = lane >> 4, l16 = lane & 15;
    int wm = (wv & 1) * 64, wn = (wv >> 1) * 64;

    int arow[4];
#pragma unroll
    for (int i = 0; i < 4; i++) {
        int r = mbase + wm + i * 16 + l16;
        arow[i] = (r > 1000) ? 1000 : r;
    }
    const _Float16* Bbase = Bw + (size_t)(bn + wn + l16) * 512 + koff + quad * 8;

    f32x4 acc[4][4] = {};
    for (int kk = 0; kk < 256; kk += 32) {
        half8 a[4], b[4];
#pragma unroll
        for (int i = 0; i < 4; i++)
            a[i] = *(const half8*)(A + (size_t)arow[i] * 256 + quad * 8 + kk);
#pragma unroll
        for (int j = 0; j < 4; j++)
            b[j] = *(const half8*)(Bbase + (size_t)j * 16 * 512 + kk);
#pragma unroll
        for (int i = 0; i < 4; i++)
#pragma unroll
            for (int j = 0; j < 4; j++)
                acc[i][j] = __builtin_amdgcn_mfma_f32_16x16x32_f16(a[i], b[j], acc[i][j], 0, 0, 0);
    }
#pragma unroll
    for (int j = 0; j < 4; j++) {
        int col = bn + wn + j * 16 + l16;
        float qv = qvec[which * 1024 + col];
        int perm = ((col & 255) >> 5) * 128 + (col & 15) * 8 + ((col >> 8) * 2 + ((col >> 4) & 1));
#pragma unroll
        for (int i = 0; i < 4; i++) {
            int row = mbase + wm + i * 16 + quad * 4;
#pragma unroll
            for (int r = 0; r < 4; r++) {
                if (row + r > 1000) continue;
                Tsw[(size_t)((which << 10) + row + r) * 1024 + perm] = (_Float16)(acc[i][j][r] + qv);
            }
        }
    }
}

// ---------------------------------------------------------------------------
// LSTM, R6. 32 WGs x 512 threads (8 waves, 2/SIMD). WG owns batch rows
// {2*bid, 2*bid+1}. Wave w owns hidden cols [32w,32w+32) as before.
// hA rows 2..15 are permanently ZERO (garbage acc rows discarded).
// After MFMA, quad-0 lanes hold the 2 real rows' preacts; they bounce them
// through a per-wave 1KB LDS region (4 ds_write_b128 + 1 ds_read_b128,
// same-wave ordering -> no barrier), so EVERY lane does exactly 1 gate
// update (row = lane>>5, hc = lane&31): 5 trans/lane vs 40 before.
// Whh frags: k<6 in VGPR (48 frags, 192 AGPR + 32 acc), k>=6 in LDS (16/wave).
// hA double-buffered -> one __syncthreads per step.
// ---------------------------------------------------------------------------
__global__ __launch_bounds__(512, 2) void lstm_kernel(
        const float* __restrict__ Whh,          // [1024][256] f32
        const _Float16* __restrict__ Tsw,       // [2048][1024] f16 permuted
        const int* __restrict__ ridxArr,        // [B*S]
        _Float16* __restrict__ outH) {          // [b*512+t][256] f16
    int bid = blockIdx.x;                       // 0..31
    int tid = threadIdx.x, wv = tid >> 6, lane = tid & 63;
    int quad = lane >> 4, l16 = lane & 15;
    int row = lane >> 5;                        // 0..1: batch row this lane updates
    int hc  = lane & 31;                        // hidden col within wave's 32

    extern __shared__ char smem[];
    _Float16* ldsB = (_Float16*)smem;                  // 8 waves * 16 frags * 512 f16 = 131072 B
    _Float16* hA   = (_Float16*)(smem + 131072);       // 2 x 8 KB, A-frag order, dbuf
    float*    rd   = (float*)(smem + 147456);          // 8 waves * 256 f32 = 8192 B

    // ---- fill Whh fragments (f32 -> f16): k<6 -> VGPR, k>=6 -> LDS ----
    half8 rB[48];
#pragma unroll
    for (int v = 0; v < 8; v++) {
#pragma unroll
        for (int k = 0; k < 8; k++) {
            int col = (v >> 1) * 256 + wv * 32 + (v & 1) * 16 + l16;
            const float* p = Whh + (size_t)col * 256 + k * 32 + quad * 8;
            float4 x0 = *(const float4*)p;
            float4 x1 = *(const float4*)(p + 4);
            half8 hb;
            hb[0] = (_Float16)x0.x; hb[1] = (_Float16)x0.y; hb[2] = (_Float16)x0.z; hb[3] = (_Float16)x0.w;
            hb[4] = (_Float16)x1.x; hb[5] = (_Float16)x1.y; hb[6] = (_Float16)x1.z; hb[7] = (_Float16)x1.w;
            if (k < 6) rB[k * 8 + v] = hb;
            else *(half8*)(ldsB + ((size_t)wv * 16 + (k - 6) * 8 + v) * 512 + lane * 8) = hb;
        }
    }
    // zero BOTH hA buffers (rows 2..15 must stay zero forever)
#pragma unroll
    for (int z = tid; z < 1024; z += 512)
        ((float4*)hA)[z] = float4{0.f, 0.f, 0.f, 0.f};

    int b0 = bid * 2 + row;
    int tb = b0 * 512;
    _Float16* po = outH + (size_t)b0 * 512 * 256 + wv * 32 + hc;

    float c = 0.f;
    // prologue gathers (1 T half8 + next ridx per lane)
    half8 Tcur;
    unsigned ridxA;
    {
        int r0 = ridxArr[tb];
        Tcur = *(const half8*)(Tsw + (size_t)r0 * 1024 + wv * 128 + (hc & 15) * 8);
        ridxA = ridxArr[tb + 1];
    }
    __syncthreads();

    int cur = 0;
    for (int t = 0; t < 512; t++) {
        // prefetch next T row + index two ahead
        int tn2 = (t + 2 < 512) ? t + 2 : 511;
        half8 Tnx = *(const half8*)(Tsw + (size_t)ridxA * 1024 + wv * 128 + (hc & 15) * 8);
        unsigned ridxB = ridxArr[tb + tn2];

        f32x4 acc[8];
#pragma unroll
        for (int v = 0; v < 8; v++) acc[v] = f32x4{0.f, 0.f, 0.f, 0.f};

        const _Float16* hAc = hA + cur * 4096;
#pragma unroll
        for (int k = 0; k < 8; k++) {
            half8 av = *(const half8*)(hAc + k * 512 + lane * 8);
#pragma unroll
            for (int v = 0; v < 8; v++) {
                half8 bv;
                if (k < 6) bv = rB[k * 8 + v];
                else bv = *(const half8*)(ldsB + ((size_t)wv * 16 + (k - 6) * 8 + v) * 512 + lane * 8);
                acc[v] = __builtin_amdgcn_mfma_f32_16x16x32_f16(av, bv, acc[v], 0, 0, 0);
            }
        }

        // ---- in-wave redistribution: quad0's 2 real rows -> all 64 lanes ----
        // rd layout (f32, per wave 256): r2*128 + l16*8 + par*4 + gate
        if (quad == 0) {
#pragma unroll
            for (int r2 = 0; r2 < 2; r2++)
#pragma unroll
                for (int par = 0; par < 2; par++) {
                    f32x4 pv;
                    pv[0] = acc[0 + par][r2];
                    pv[1] = acc[2 + par][r2];
                    pv[2] = acc[4 + par][r2];
                    pv[3] = acc[6 + par][r2];
                    *(f32x4*)(rd + wv * 256 + r2 * 128 + l16 * 8 + par * 4) = pv;
                }
        }
        int pr = hc >> 4;
        f32x4 pa = *(const f32x4*)(rd + wv * 256 + row * 128 + (hc & 15) * 8 + pr * 4);

        // T gate values: half8 elem = 2*gate + pr (pr uniform-per-lane runtime -> cndmask)
        float tg0 = pr ? (float)Tcur[1] : (float)Tcur[0];
        float tg1 = pr ? (float)Tcur[3] : (float)Tcur[2];
        float tg2 = pr ? (float)Tcur[5] : (float)Tcur[4];
        float tg3 = pr ? (float)Tcur[7] : (float)Tcur[6];

        float ii = sigm(pa[0] + tg0);
        float ff = sigm(pa[1] + tg1);
        float gg = tanh_(pa[2] + tg2);
        float oo = sigm(pa[3] + tg3);
        c = ff * c + ii * gg;
        float h = oo * tanh_(c);
        _Float16 hf = (_Float16)h;

        // write new h into the OTHER hA buffer (A-frag layout, rows 0..1 only)
        hA[(cur ^ 1) * 4096 + wv * 512 + (hc >> 3) * 128 + row * 8 + (hc & 7)] = hf;

        __syncthreads();   // hA[cur^1] complete for step t+1
        cur ^= 1;

        // post-barrier: outH store drains during next step's compute
        po[0] = hf;
        po += 256;
        Tcur = Tnx;
        ridxA = ridxB;
    }
}

// ---------------------------------------------------------------------------
// Generic f16 MFMA GEMM: C = A @ Bw^T (+bias), epi 1 = sigmoid. Direct-global.
// ---------------------------------------------------------------------------
__global__ __launch_bounds__(256) void gemm_f16(
        const _Float16* __restrict__ A, const _Float16* __restrict__ Bw,
        const float* __restrict__ bias, float* __restrict__ C,
        int K, int ldC, int Nstore, int epi) {
    int bm = blockIdx.x * 128, bn = blockIdx.y * 128;
    int tid = threadIdx.x, wv = tid >> 6, lane = tid & 63;
    int quad = lane >> 4, l16 = lane & 15;
    int wm = (wv & 1) * 64, wn = (wv >> 1) * 64;

    const _Float16* Abase = A + (size_t)(bm + wm + l16) * K + quad * 8;
    const _Float16* Bbase = Bw + (size_t)(bn + wn + l16) * K + quad * 8;

    f32x4 acc[4][4] = {};
    for (int kk = 0; kk < K; kk += 32) {
        half8 a[4], b[4];
#pragma unroll
        for (int i = 0; i < 4; i++) a[i] = *(const half8*)(Abase + (size_t)i * 16 * K + kk);
#pragma unroll
        for (int j = 0; j < 4; j++) b[j] = *(const half8*)(Bbase + (size_t)j * 16 * K + kk);
#pragma unroll
        for (int i = 0; i < 4; i++)
#pragma unroll
            for (int j = 0; j < 4; j++)
                acc[i][j] = __builtin_amdgcn_mfma_f32_16x16x32_f16(a[i], b[j], acc[i][j], 0, 0, 0);
    }
#pragma unroll
    for (int j = 0; j < 4; j++) {
        int col = bn + wn + j * 16 + l16;
        if (col >= Nstore) continue;
        float bv = bias ? bias[col] : 0.f;
#pragma unroll
        for (int i = 0; i < 4; i++) {
            int row0 = bm + wm + i * 16 + quad * 4;
#pragma unroll
            for (int r = 0; r < 4; r++) {
                float v = acc[i][j][r] + bv;
                if (epi == 1) v = sigm(v);
                C[(size_t)(row0 + r) * ldC + col] = v;
            }
        }
    }
}

// ---------------------------------------------------------------------------
__global__ void att_kernel(const float* __restrict__ mlpout, const float* __restrict__ simW,
                           float* __restrict__ att) {
    int m = blockIdx.x * 256 + threadIdx.x;
    float s = 0.f;
#pragma unroll
    for (int d = 0; d < 80; d += 4) {
        float4 v = *(const float4*)(mlpout + (size_t)m * 80 + d);
        float4 w = *(const float4*)(simW + d);
        s += tanh_(v.x) * w.x + tanh_(v.y) * w.y + tanh_(v.z) * w.z + tanh_(v.w) * w.w;
    }
    att[m] = s;
}

// ---------------------------------------------------------------------------
// Attention as prefix scan; writes final = [attn_cum_1 | out] f16.
// ---------------------------------------------------------------------------
__global__ __launch_bounds__(256) void scan_kernel(const float* __restrict__ att,
                                                   const _Float16* __restrict__ outH,
                                                   _Float16* __restrict__ finalB) {
    int b = blockIdx.x, d = threadIdx.x;
    __shared__ float w_s[512];
    for (int i = d; i < 512; i += 256) w_s[i] = __expf(att[(size_t)b * 512 + i]);
    __syncthreads();

    float S = 0.f, W = 0.f, C = 0.f;
    const _Float16* op = outH + (size_t)b * 512 * 256 + d;
    _Float16* fp = finalB + (size_t)b * 512 * 512 + d;
    for (int i = 0; i < 512; i++) {
        float w = w_s[i];
        float ov = (float)op[(size_t)i * 256];
        S += w * ov;
        W += w;
        float ao = S * __builtin_amdgcn_rcpf(W);
        fp[(size_t)i * 512]       = (_Float16)C;
        fp[(size_t)i * 512 + 256] = (_Float16)ov;
        C += ao;
    }
}

// ---------------------------------------------------------------------------
extern "C" void kernel_launch(void* const* d_in, const int* in_sizes, int n_in,
                              void* d_out, int out_size, void* d_ws, size_t ws_size,
                              hipStream_t stream) {
    const int*   skill      = (const int*)d_in[0];
    const int*   answer     = (const int*)d_in[1];
    const float* skill_emb  = (const float*)d_in[2];
    const float* answer_emb = (const float*)d_in[3];
    const float* Wih        = (const float*)d_in[4];
    const float* Whh        = (const float*)d_in[5];
    const float* bih        = (const float*)d_in[6];
    const float* bhh        = (const float*)d_in[7];
    const float* mlp_W      = (const float*)d_in[8];
    const float* mlp_b      = (const float*)d_in[9];
    const float* sim_W      = (const float*)d_in[10];
    const float* fc_W       = (const float*)d_in[11];
    const float* fc_b       = (const float*)d_in[12];

    float* res    = (float*)d_out;               // [32768][1000]
    float* sa_out = res + (size_t)BS * NC;       // [32768][512]

    char* ws = (char*)d_ws;
    _Float16* outH   = (_Float16*)(ws);                 // 16,777,216 B
    _Float16* finalB = (_Float16*)(ws + 16777216);      // 33,554,432
    _Float16* wih16  = (_Float16*)(ws + 50331648);      //  1,048,576
    _Float16* fcw16  = (_Float16*)(ws + 51380224);      //  1,048,576
    _Float16* mlpw16 = (_Float16*)(ws + 52428800);      //     65,536
    _Float16* se16   = (_Float16*)(ws + 52494336);      //    524,288 (512,512 used)
    float*    bsum   = (float*)(ws + 53018624);         //      4,096
    float*    qvec   = (float*)(ws + 53022720);         //      8,192
    float*    att    = (float*)(ws + 53030912);         //    131,072
    float*    mlpout = (float*)(ws + 53161984);         // 10,485,760
    _Float16* Tsw    = (_Float16*)(ws + 63647744);      //  4,194,304
    int*      ridx   = (int*)(ws + 67842048);           //    131,072

    (void)bsum; (void)in_sizes; (void)n_in; (void)out_size; (void)ws_size;

    hipLaunchKernelGGL(prep_kernel, dim3(5238), dim3(256), 0, stream,
                       Wih, fc_W, mlp_W, skill_emb, answer_emb, bih, bhh,
                       wih16, fcw16, mlpw16, se16, bsum, qvec);
    hipLaunchKernelGGL(embed_kernel, dim3(BS), dim3(128), 0, stream,
                       skill, answer, skill_emb, answer_emb, sa_out, ridx);
    hipLaunchKernelGGL(tgemm_kernel, dim3(16, 8), dim3(256), 0, stream,
                       se16, wih16, qvec, Tsw);

    hipFuncSetAttribute((const void*)lstm_kernel,
                        hipFuncAttributeMaxDynamicSharedMemorySize, 155648);
    hipLaunchKernelGGL(lstm_kernel, dim3(32), dim3(512), 155648, stream,
                       Whh, Tsw, ridx, outH);

    hipLaunchKernelGGL(gemm_f16, dim3(256, 1), dim3(256), 0, stream,
                       outH, mlpw16, mlp_b, mlpout, 256, 80, 80, 0);
    hipLaunchKernelGGL(att_kernel, dim3(128), dim3(256), 0, stream, mlpout, sim_W, att);
    hipLaunchKernelGGL(scan_kernel, dim3(64), dim3(256), 0, stream, att, outH, finalB);
    hipLaunchKernelGGL(gemm_f16, dim3(256, 8), dim3(256), 0, stream,
                       finalB, fcw16, fc_b, res, 512, 1000, 1000, 1);
}